// Round 16
// baseline (157.169 us; speedup 1.0000x reference)
//
#include <hip/hip_runtime.h>
#include <string.h>

// Exact k-th order statistic + mask, fp32, n = 64*1024*1024.
// Fused single-full-pass, 16KB-LDS (8 blocks/CU occupancy):
//   k1_fused : read x, write PROVISIONAL mask (u >= u0+NWIN);
//              single 4096-bin LDS hist of below-u0 elements keyed by uniform
//              low mantissa bits (10.5% fire); 1-ulp window global hist +
//              per-block compaction (0.035% fire)
//   anchor_select : below = sum(g); exact verify + window select -> thr
//   fixup : scatter 1.0f for the ~23K window elems >= thr (gated flag==0)
//   fallback : proven 3-pass radix + FULL re-mask, always enqueued, flag-gated
//
// state: [3]=flag [8]=thr mapped-u [9]=thr float bits [10..15]=fb chain
// ws ints: ST(32)|G(4096)|HWIN(16384)|FB1(4096)|FB2(4096)|FB3(256)|CNTB(2048)
//          <- all zeroed | CAND(2048 blocks x 256 x uint2)

#define N_STATE  32
#define G_OFF    32
#define HWIN_OFF (G_OFF + 4096)
#define NWIN     16384
#define FB1_OFF  (HWIN_OFF + NWIN)
#define FB2_OFF  (FB1_OFF + 4096)
#define FB3_OFF  (FB2_OFF + 4096)
#define CNTB_OFF (FB3_OFF + 256)
#define NBLK     2048
#define FIXED_Z  (CNTB_OFF + NBLK)            // ~124 KB zeroed per call
#define CAND_OFF FIXED_Z
#define BSEG     256u

#define FB_WS_INTS (16 + 4096 + 4096 + 256)

__device__ __forceinline__ unsigned map_bits(unsigned raw) {
    return (raw & 0x80000000u) ? ~raw : (raw | 0x80000000u);
}

// ---------------- workspace zeroing ----------------
__global__ void __launch_bounds__(256)
zero_ws(uint4* __restrict__ p, int n16)
{
    int i = blockIdx.x * 256 + threadIdx.x;
    int s = gridDim.x * 256;
    uint4 z = make_uint4(0u, 0u, 0u, 0u);
    for (; i < n16; i += s) p[i] = z;
}

// ---------------- k1: fused mask + below-hist + window compaction ----------
__global__ void __launch_bounds__(256)
k1_fused(const uint4* __restrict__ x, int n4, float4* __restrict__ out,
         unsigned* __restrict__ g, unsigned* __restrict__ hwin,
         uint2* __restrict__ cand, unsigned* __restrict__ cntb, unsigned u0)
{
    __shared__ unsigned c[4096];
    __shared__ unsigned bcnt;
    for (int i = threadIdx.x; i < 4096; i += 256) c[i] = 0u;
    if (threadIdx.x == 0) bcnt = 0u;
    __syncthreads();

    uint2* seg = cand + (size_t)blockIdx.x * BSEG;
    const unsigned hiw = u0 + (unsigned)NWIN;
    int idx = blockIdx.x * 256 + threadIdx.x;
    int S = gridDim.x * 256;
    for (int i = idx; i < n4; i += S) {
        uint4 v = x[i];
        float4 o;
        unsigned gi = (unsigned)i * 4u;
        unsigned u;
        #define STEP(C, OFS, OC) { \
            u = map_bits(v.C); \
            OC = (u >= hiw) ? 1.0f : 0.0f; \
            if (u < u0) { \
                atomicAdd(&c[u & 4095u], 1u); \
            } else if (u < hiw) { \
                atomicAdd(&hwin[u - u0], 1u); \
                unsigned slot = atomicAdd(&bcnt, 1u); \
                if (slot < BSEG) seg[slot] = make_uint2(u, gi + OFS); } }
        STEP(x, 0u, o.x) STEP(y, 1u, o.y) STEP(z, 2u, o.z) STEP(w, 3u, o.w)
        #undef STEP
        out[i] = o;
    }
    __syncthreads();
    for (int i = threadIdx.x; i < 4096; i += 256) {
        unsigned a = c[i];
        if (a) atomicAdd(&g[i], a);
    }
    if (threadIdx.x == 0) cntb[blockIdx.x] = bcnt;
}

// ---------------- exact anchor + verification + window select ----------------
__global__ void __launch_bounds__(1024)
anchor_select(const unsigned* __restrict__ g, const unsigned* __restrict__ hwin,
              const unsigned* __restrict__ cntb, unsigned r, unsigned u0,
              unsigned* __restrict__ st)
{
    __shared__ unsigned s[1024];
    __shared__ unsigned sm[1024];
    __shared__ unsigned sh_below, sh_rank, sh_flag, sh_max;
    int t = threadIdx.x;

    // phase 1: below = sum of all g bins; max of per-block counts
    unsigned part = g[t] + g[t + 1024] + g[t + 2048] + g[t + 3072];
    unsigned mx = 0;
    for (int j = t; j < NBLK; j += 1024) {
        unsigned cc = cntb[j];
        mx = (cc > mx) ? cc : mx;
    }
    s[t] = part; sm[t] = mx;
    __syncthreads();
    for (int off = 512; off > 0; off >>= 1) {
        if (t < off) {
            s[t] += s[t + off];
            sm[t] = (sm[t + off] > sm[t]) ? sm[t + off] : sm[t];
        }
        __syncthreads();
    }
    if (t == 0) { sh_below = s[0]; sh_max = sm[0]; }
    __syncthreads();

    // phase 2: prefix over hwin (16 bins/thread)
    unsigned loc[16];
    unsigned mySum = 0;
    int base = t * 16;
    #pragma unroll
    for (int j = 0; j < 16; ++j) { loc[j] = hwin[base + j]; mySum += loc[j]; }
    s[t] = mySum;
    __syncthreads();
    for (int off = 1; off < 1024; off <<= 1) {
        unsigned v = (t >= off) ? s[t - off] : 0u;
        __syncthreads();
        s[t] += v;
        __syncthreads();
    }
    unsigned Nwin = s[1023];
    if (t == 0) {
        unsigned long long below = sh_below;
        unsigned flag = 0;
        if (sh_max > BSEG) flag = 1;          // block segment overflow
        if (!((below <= (unsigned long long)r) &&
              ((unsigned long long)r < below + (unsigned long long)Nwin))) flag = 1;
        st[3] = flag;
        sh_flag = flag;
        sh_rank = (unsigned)((unsigned long long)r - below);
    }
    __syncthreads();
    if (sh_flag != 0u) return;
    unsigned rank = sh_rank;
    unsigned incl = s[t], excl = incl - mySum;
    if (rank >= excl && rank < incl) {
        unsigned run = excl;
        #pragma unroll
        for (int j = 0; j < 16; ++j) {
            if (rank < run + loc[j]) {
                unsigned u = u0 + (unsigned)(base + j);
                st[8] = u;                                            // mapped thr
                st[9] = (u & 0x80000000u) ? (u & 0x7FFFFFFFu) : ~u;   // float bits
                break;
            }
            run += loc[j];
        }
    }
}

// ---------------- fixup (gated flag==0) ----------------
__global__ void __launch_bounds__(64)
fixup(const uint2* __restrict__ cand, const unsigned* __restrict__ cntb,
      const unsigned* __restrict__ st, float* __restrict__ out)
{
    if (st[3] != 0u) return;
    unsigned thr = st[8];
    unsigned b = blockIdx.x;
    unsigned m = cntb[b]; if (m > BSEG) m = BSEG;
    const uint2* seg = cand + (size_t)b * BSEG;
    for (unsigned j = threadIdx.x; j < m; j += 64u) {
        uint2 cv = seg[j];
        if (cv.x >= thr) out[cv.y] = 1.0f;
    }
}

// ---------------- fallback (proven 3-pass radix), flag-gated ----------------
__global__ void __launch_bounds__(256)
hist_pass(const uint4* __restrict__ x, int n4, int shift, int nbins, int mode,
          const unsigned* __restrict__ state, unsigned* __restrict__ hist,
          const unsigned* __restrict__ gate)
{
    if (gate && *gate == 0u) return;
    __shared__ unsigned lh[4096];
    for (int i = threadIdx.x; i < nbins; i += blockDim.x) lh[i] = 0u;
    __syncthreads();

    unsigned tgt = 0; int mshift = 0;
    if (mode == 1)      { tgt = state[0];                      mshift = 20; }
    else if (mode == 2) { tgt = (state[0] << 12) | state[2];   mshift = 8;  }

    const unsigned binmask = (unsigned)(nbins - 1);
    int idx = blockIdx.x * blockDim.x + threadIdx.x;
    int stride = gridDim.x * blockDim.x;
    for (int i = idx; i < n4; i += stride) {
        uint4 v = x[i];
        unsigned u;
        u = map_bits(v.x); if (!mode || (u >> mshift) == tgt) atomicAdd(&lh[(u >> shift) & binmask], 1u);
        u = map_bits(v.y); if (!mode || (u >> mshift) == tgt) atomicAdd(&lh[(u >> shift) & binmask], 1u);
        u = map_bits(v.z); if (!mode || (u >> mshift) == tgt) atomicAdd(&lh[(u >> shift) & binmask], 1u);
        u = map_bits(v.w); if (!mode || (u >> mshift) == tgt) atomicAdd(&lh[(u >> shift) & binmask], 1u);
    }
    __syncthreads();
    for (int i = threadIdx.x; i < nbins; i += blockDim.x) {
        unsigned c = lh[i];
        if (c) atomicAdd(&hist[i], c);
    }
}

__global__ void __launch_bounds__(1024)
scan_select(const unsigned* __restrict__ hist, int nbins,
            const unsigned* __restrict__ rank_in, unsigned rank_imm,
            unsigned* __restrict__ bin_out, unsigned* __restrict__ rank_out,
            const unsigned* __restrict__ gate, int want_nonzero)
{
    if (gate) {
        unsigned g = *gate;
        if ((g != 0u) != (want_nonzero != 0)) return;
    }
    __shared__ unsigned s[1024];
    int t = threadIdx.x;
    unsigned rank = rank_in ? *rank_in : rank_imm;
    int per = (nbins + 1023) >> 10;
    int base = t * per;
    unsigned mySum = 0;
    for (int i = 0; i < per; ++i) {
        int b = base + i;
        if (b < nbins) mySum += hist[b];
    }
    s[t] = mySum;
    __syncthreads();
    for (int off = 1; off < 1024; off <<= 1) {
        unsigned v = (t >= off) ? s[t - off] : 0u;
        __syncthreads();
        s[t] += v;
        __syncthreads();
    }
    unsigned incl = s[t];
    unsigned excl = incl - mySum;
    if (rank >= excl && rank < incl) {
        unsigned run = excl;
        for (int i = 0; i < per; ++i) {
            int b = base + i;
            unsigned c = (b < nbins) ? hist[b] : 0u;
            if (rank < run + c) { *bin_out = (unsigned)b; *rank_out = rank - run; break; }
            run += c;
        }
    }
}

__global__ void finalize_thr_fb(unsigned* st, const unsigned* gate) {
    if (gate && *gate == 0u) return;
    unsigned u = (st[10] << 20) | (st[12] << 8) | st[14];
    st[9] = (u & 0x80000000u) ? (u & 0x7FFFFFFFu) : ~u;
}

// ---------------- full re-mask (fallback path only, flag-gated) ------------
__global__ void __launch_bounds__(256)
mask_kernel(const float4* __restrict__ x, float4* __restrict__ out, int n4,
            const unsigned* __restrict__ st, const unsigned* __restrict__ gate)
{
    if (gate && *gate == 0u) return;
    float thr = __uint_as_float(st[9]);
    int idx = blockIdx.x * blockDim.x + threadIdx.x;
    int stride = gridDim.x * blockDim.x;
    for (int i = idx; i < n4; i += stride) {
        float4 v = x[i];
        float4 o;
        o.x = (v.x >= thr) ? 1.0f : 0.0f;
        o.y = (v.y >= thr) ? 1.0f : 0.0f;
        o.z = (v.z >= thr) ? 1.0f : 0.0f;
        o.w = (v.w >= thr) ? 1.0f : 0.0f;
        out[i] = o;
    }
}

// ---------------- host ----------------
static inline unsigned host_map(float f) {
    unsigned raw; memcpy(&raw, &f, 4);
    return (raw & 0x80000000u) ? ~raw : (raw | 0x80000000u);
}

extern "C" void kernel_launch(void* const* d_in, const int* in_sizes, int n_in,
                              void* d_out, int out_size, void* d_ws, size_t ws_size,
                              hipStream_t stream)
{
    const float* x = (const float*)d_in[0];
    float* out = (float*)d_out;
    long long n = (long long)in_sizes[0];
    long long k = (long long)((double)n * 0.9);   // matches Python int(n * RATIO)

    if (k <= 0) {
        hipMemsetAsync(d_out, 0, (size_t)out_size * sizeof(float), stream);
        return;
    }

    unsigned* ws = (unsigned*)d_ws;
    unsigned* st = ws;
    int n4 = (int)(n / 4);
    const uint4* x4 = (const uint4*)x;
    unsigned r = (unsigned)(n - k);               // ascending rank of threshold

    size_t need_fast = ((size_t)CAND_OFF + (size_t)NBLK * BSEG * 2) * 4;

    if (ws_size >= need_fast) {
        unsigned* g    = ws + G_OFF;
        unsigned* hwin = ws + HWIN_OFF;
        unsigned* fb1  = ws + FB1_OFF;
        unsigned* fb2  = ws + FB2_OFF;
        unsigned* fb3  = ws + FB3_OFF;
        unsigned* cntb = ws + CNTB_OFF;
        uint2*    cand = (uint2*)(ws + CAND_OFF);

        // Static window around the 0.1-quantile of N(0,1), u* = map(-1.2816):
        // window = 16384 ulp ~= +-4.7 sigma of the sample-quantile position.
        // Exactness NEVER depends on it: flag-verified, fallback-gated.
        unsigned ustar = host_map(-1.2816f);
        unsigned u0 = ustar - (unsigned)(NWIN / 2);

        zero_ws<<<64, 256, 0, stream>>>((uint4*)d_ws, (FIXED_Z + 3) / 4);
        k1_fused<<<NBLK, 256, 0, stream>>>(x4, n4, (float4*)out, g, hwin,
                                           cand, cntb, u0);
        anchor_select<<<1, 1024, 0, stream>>>(g, hwin, cntb, r, u0, st);
        fixup<<<NBLK, 64, 0, stream>>>(cand, cntb, st, out);
        // fallback chain (gated on flag!=0) — proven exact path, writes st[9]
        hist_pass<<<1024, 256, 0, stream>>>(x4, n4, 20, 4096, 0, &st[10], fb1, &st[3]);
        scan_select<<<1, 1024, 0, stream>>>(fb1, 4096, nullptr, r, &st[10], &st[11], &st[3], 1);
        hist_pass<<<1024, 256, 0, stream>>>(x4, n4, 8, 4096, 1, &st[10], fb2, &st[3]);
        scan_select<<<1, 1024, 0, stream>>>(fb2, 4096, &st[11], 0u, &st[12], &st[13], &st[3], 1);
        hist_pass<<<1024, 256, 0, stream>>>(x4, n4, 0, 256, 2, &st[10], fb3, &st[3]);
        scan_select<<<1, 1024, 0, stream>>>(fb3, 256, &st[13], 0u, &st[14], &st[15], &st[3], 1);
        finalize_thr_fb<<<1, 1, 0, stream>>>(st, &st[3]);
        mask_kernel<<<2048, 256, 0, stream>>>((const float4*)x, (float4*)out, n4, st, &st[3]);
    } else {
        // small-ws standalone fallback: 3-pass radix + mask (ungated)
        unsigned* h1 = ws + 16;
        unsigned* h2 = ws + 16 + 4096;
        unsigned* h3 = ws + 16 + 8192;

        hipMemsetAsync(d_ws, 0, FB_WS_INTS * sizeof(unsigned), stream);

        hist_pass<<<2048, 256, 0, stream>>>(x4, n4, 20, 4096, 0, &ws[10], h1, nullptr);
        scan_select<<<1, 1024, 0, stream>>>(h1, 4096, nullptr, r, &ws[10], &ws[11], nullptr, 0);
        hist_pass<<<2048, 256, 0, stream>>>(x4, n4, 8, 4096, 1, &ws[10], h2, nullptr);
        scan_select<<<1, 1024, 0, stream>>>(h2, 4096, &ws[11], 0u, &ws[12], &ws[13], nullptr, 0);
        hist_pass<<<2048, 256, 0, stream>>>(x4, n4, 0, 256, 2, &ws[10], h3, nullptr);
        scan_select<<<1, 1024, 0, stream>>>(h3, 256, &ws[13], 0u, &ws[14], &ws[15], nullptr, 0);
        finalize_thr_fb<<<1, 1, 0, stream>>>(ws, nullptr);
        mask_kernel<<<2048, 256, 0, stream>>>((const float4*)x, (float4*)out, n4, ws, nullptr);
    }
}

// Round 17
// 143.887 us; speedup vs baseline: 1.0923x; 1.0923x over previous
//
#include <hip/hip_runtime.h>
#include <string.h>

// Exact k-th order statistic + mask, fp32, n = 64*1024*1024.
// Fused single-full-pass, COUNT-not-histogram anchor:
//   k1_fused : read x, write PROVISIONAL mask (u >= u0+NWIN);
//              per-uint4 below-count -> ONE private-slot LDS atomic;
//              1-ulp window global hist + per-block compaction behind a
//              wave-skippable (98%) combined branch
//   anchor_select : below = st[2]; exact verify + window select -> thr
//   fixup : scatter 1.0f for the ~23K window elems >= thr (gated flag==0)
//   fallback : proven 3-pass radix + FULL re-mask, always enqueued, flag-gated
//
// state: [2]=below [3]=flag [8]=thr mapped-u [9]=thr float bits [10..15]=fb
// ws ints: ST(32)|HWIN(16384)|FB1(4096)|FB2(4096)|FB3(256)|CNTB(2048)
//          <- all zeroed | CAND(2048 blocks x 256 x uint2)

#define N_STATE  32
#define HWIN_OFF 32
#define NWIN     16384
#define FB1_OFF  (HWIN_OFF + NWIN)
#define FB2_OFF  (FB1_OFF + 4096)
#define FB3_OFF  (FB2_OFF + 4096)
#define CNTB_OFF (FB3_OFF + 256)
#define NBLK     2048
#define FIXED_Z  (CNTB_OFF + NBLK)            // ~105 KB zeroed per call
#define CAND_OFF FIXED_Z
#define BSEG     256u

#define FB_WS_INTS (16 + 4096 + 4096 + 256)

__device__ __forceinline__ unsigned map_bits(unsigned raw) {
    return (raw & 0x80000000u) ? ~raw : (raw | 0x80000000u);
}

// ---------------- workspace zeroing ----------------
__global__ void __launch_bounds__(256)
zero_ws(uint4* __restrict__ p, int n16)
{
    int i = blockIdx.x * 256 + threadIdx.x;
    int s = gridDim.x * 256;
    uint4 z = make_uint4(0u, 0u, 0u, 0u);
    for (; i < n16; i += s) p[i] = z;
}

// ---------------- k1: fused mask + below-count + window compaction ---------
__global__ void __launch_bounds__(256)
k1_fused(const uint4* __restrict__ x, int n4, float4* __restrict__ out,
         unsigned* __restrict__ st, unsigned* __restrict__ hwin,
         uint2* __restrict__ cand, unsigned* __restrict__ cntb, unsigned u0)
{
    __shared__ unsigned c[256];
    __shared__ unsigned bcnt;
    c[threadIdx.x] = 0u;
    if (threadIdx.x == 0) bcnt = 0u;
    __syncthreads();

    uint2* seg = cand + (size_t)blockIdx.x * BSEG;
    const unsigned hiw = u0 + (unsigned)NWIN;
    int idx = blockIdx.x * 256 + threadIdx.x;
    int S = gridDim.x * 256;
    for (int i = idx; i < n4; i += S) {
        uint4 v = x[i];
        float4 o;
        unsigned ua = map_bits(v.x), ub = map_bits(v.y);
        unsigned uc = map_bits(v.z), ud = map_bits(v.w);
        o.x = (ua >= hiw) ? 1.0f : 0.0f;
        o.y = (ub >= hiw) ? 1.0f : 0.0f;
        o.z = (uc >= hiw) ? 1.0f : 0.0f;
        o.w = (ud >= hiw) ? 1.0f : 0.0f;
        unsigned cnt4 = (ua < u0 ? 1u : 0u) + (ub < u0 ? 1u : 0u)
                      + (uc < u0 ? 1u : 0u) + (ud < u0 ? 1u : 0u);
        atomicAdd(&c[threadIdx.x], cnt4);      // private slot: no contention
        bool wa = (ua - u0) < (unsigned)NWIN;
        bool wb = (ub - u0) < (unsigned)NWIN;
        bool wc = (uc - u0) < (unsigned)NWIN;
        bool wd = (ud - u0) < (unsigned)NWIN;
        if (wa | wb | wc | wd) {               // wave-skipped ~98% of the time
            unsigned gi = (unsigned)i * 4u;
            if (wa) { atomicAdd(&hwin[ua - u0], 1u);
                      unsigned sl = atomicAdd(&bcnt, 1u);
                      if (sl < BSEG) seg[sl] = make_uint2(ua, gi + 0u); }
            if (wb) { atomicAdd(&hwin[ub - u0], 1u);
                      unsigned sl = atomicAdd(&bcnt, 1u);
                      if (sl < BSEG) seg[sl] = make_uint2(ub, gi + 1u); }
            if (wc) { atomicAdd(&hwin[uc - u0], 1u);
                      unsigned sl = atomicAdd(&bcnt, 1u);
                      if (sl < BSEG) seg[sl] = make_uint2(uc, gi + 2u); }
            if (wd) { atomicAdd(&hwin[ud - u0], 1u);
                      unsigned sl = atomicAdd(&bcnt, 1u);
                      if (sl < BSEG) seg[sl] = make_uint2(ud, gi + 3u); }
        }
        out[i] = o;
    }
    __syncthreads();
    for (int off = 128; off > 0; off >>= 1) {
        if (threadIdx.x < (unsigned)off) c[threadIdx.x] += c[threadIdx.x + off];
        __syncthreads();
    }
    if (threadIdx.x == 0) {
        atomicAdd(&st[2], c[0]);
        cntb[blockIdx.x] = bcnt;
    }
}

// ---------------- exact anchor + verification + window select ----------------
__global__ void __launch_bounds__(1024)
anchor_select(const unsigned* __restrict__ hwin, const unsigned* __restrict__ cntb,
              unsigned r, unsigned u0, unsigned* __restrict__ st)
{
    __shared__ unsigned s[1024];
    __shared__ unsigned sm[1024];
    __shared__ unsigned sh_rank, sh_flag, sh_max;
    int t = threadIdx.x;

    // phase 1: max of per-block counts
    unsigned mx = 0;
    for (int j = t; j < NBLK; j += 1024) {
        unsigned cc = cntb[j];
        mx = (cc > mx) ? cc : mx;
    }
    sm[t] = mx;
    __syncthreads();
    for (int off = 512; off > 0; off >>= 1) {
        if (t < off) sm[t] = (sm[t + off] > sm[t]) ? sm[t + off] : sm[t];
        __syncthreads();
    }
    if (t == 0) sh_max = sm[0];
    __syncthreads();

    // phase 2: prefix over hwin (16 bins/thread)
    unsigned loc[16];
    unsigned mySum = 0;
    int base = t * 16;
    #pragma unroll
    for (int j = 0; j < 16; ++j) { loc[j] = hwin[base + j]; mySum += loc[j]; }
    s[t] = mySum;
    __syncthreads();
    for (int off = 1; off < 1024; off <<= 1) {
        unsigned v = (t >= off) ? s[t - off] : 0u;
        __syncthreads();
        s[t] += v;
        __syncthreads();
    }
    unsigned Nwin = s[1023];
    if (t == 0) {
        unsigned long long below = st[2];
        unsigned flag = 0;
        if (sh_max > BSEG) flag = 1;          // block segment overflow
        if (!((below <= (unsigned long long)r) &&
              ((unsigned long long)r < below + (unsigned long long)Nwin))) flag = 1;
        st[3] = flag;
        sh_flag = flag;
        sh_rank = (unsigned)((unsigned long long)r - below);
    }
    __syncthreads();
    if (sh_flag != 0u) return;
    unsigned rank = sh_rank;
    unsigned incl = s[t], excl = incl - mySum;
    if (rank >= excl && rank < incl) {
        unsigned run = excl;
        #pragma unroll
        for (int j = 0; j < 16; ++j) {
            if (rank < run + loc[j]) {
                unsigned u = u0 + (unsigned)(base + j);
                st[8] = u;                                            // mapped thr
                st[9] = (u & 0x80000000u) ? (u & 0x7FFFFFFFu) : ~u;   // float bits
                break;
            }
            run += loc[j];
        }
    }
}

// ---------------- fixup (gated flag==0) ----------------
__global__ void __launch_bounds__(64)
fixup(const uint2* __restrict__ cand, const unsigned* __restrict__ cntb,
      const unsigned* __restrict__ st, float* __restrict__ out)
{
    if (st[3] != 0u) return;
    unsigned thr = st[8];
    unsigned b = blockIdx.x;
    unsigned m = cntb[b]; if (m > BSEG) m = BSEG;
    const uint2* seg = cand + (size_t)b * BSEG;
    for (unsigned j = threadIdx.x; j < m; j += 64u) {
        uint2 cv = seg[j];
        if (cv.x >= thr) out[cv.y] = 1.0f;
    }
}

// ---------------- fallback (proven 3-pass radix), flag-gated ----------------
__global__ void __launch_bounds__(256)
hist_pass(const uint4* __restrict__ x, int n4, int shift, int nbins, int mode,
          const unsigned* __restrict__ state, unsigned* __restrict__ hist,
          const unsigned* __restrict__ gate)
{
    if (gate && *gate == 0u) return;
    __shared__ unsigned lh[4096];
    for (int i = threadIdx.x; i < nbins; i += blockDim.x) lh[i] = 0u;
    __syncthreads();

    unsigned tgt = 0; int mshift = 0;
    if (mode == 1)      { tgt = state[0];                      mshift = 20; }
    else if (mode == 2) { tgt = (state[0] << 12) | state[2];   mshift = 8;  }

    const unsigned binmask = (unsigned)(nbins - 1);
    int idx = blockIdx.x * blockDim.x + threadIdx.x;
    int stride = gridDim.x * blockDim.x;
    for (int i = idx; i < n4; i += stride) {
        uint4 v = x[i];
        unsigned u;
        u = map_bits(v.x); if (!mode || (u >> mshift) == tgt) atomicAdd(&lh[(u >> shift) & binmask], 1u);
        u = map_bits(v.y); if (!mode || (u >> mshift) == tgt) atomicAdd(&lh[(u >> shift) & binmask], 1u);
        u = map_bits(v.z); if (!mode || (u >> mshift) == tgt) atomicAdd(&lh[(u >> shift) & binmask], 1u);
        u = map_bits(v.w); if (!mode || (u >> mshift) == tgt) atomicAdd(&lh[(u >> shift) & binmask], 1u);
    }
    __syncthreads();
    for (int i = threadIdx.x; i < nbins; i += blockDim.x) {
        unsigned c = lh[i];
        if (c) atomicAdd(&hist[i], c);
    }
}

__global__ void __launch_bounds__(1024)
scan_select(const unsigned* __restrict__ hist, int nbins,
            const unsigned* __restrict__ rank_in, unsigned rank_imm,
            unsigned* __restrict__ bin_out, unsigned* __restrict__ rank_out,
            const unsigned* __restrict__ gate, int want_nonzero)
{
    if (gate) {
        unsigned g = *gate;
        if ((g != 0u) != (want_nonzero != 0)) return;
    }
    __shared__ unsigned s[1024];
    int t = threadIdx.x;
    unsigned rank = rank_in ? *rank_in : rank_imm;
    int per = (nbins + 1023) >> 10;
    int base = t * per;
    unsigned mySum = 0;
    for (int i = 0; i < per; ++i) {
        int b = base + i;
        if (b < nbins) mySum += hist[b];
    }
    s[t] = mySum;
    __syncthreads();
    for (int off = 1; off < 1024; off <<= 1) {
        unsigned v = (t >= off) ? s[t - off] : 0u;
        __syncthreads();
        s[t] += v;
        __syncthreads();
    }
    unsigned incl = s[t];
    unsigned excl = incl - mySum;
    if (rank >= excl && rank < incl) {
        unsigned run = excl;
        for (int i = 0; i < per; ++i) {
            int b = base + i;
            unsigned c = (b < nbins) ? hist[b] : 0u;
            if (rank < run + c) { *bin_out = (unsigned)b; *rank_out = rank - run; break; }
            run += c;
        }
    }
}

__global__ void finalize_thr_fb(unsigned* st, const unsigned* gate) {
    if (gate && *gate == 0u) return;
    unsigned u = (st[10] << 20) | (st[12] << 8) | st[14];
    st[9] = (u & 0x80000000u) ? (u & 0x7FFFFFFFu) : ~u;
}

// ---------------- full re-mask (fallback path only, flag-gated) ------------
__global__ void __launch_bounds__(256)
mask_kernel(const float4* __restrict__ x, float4* __restrict__ out, int n4,
            const unsigned* __restrict__ st, const unsigned* __restrict__ gate)
{
    if (gate && *gate == 0u) return;
    float thr = __uint_as_float(st[9]);
    int idx = blockIdx.x * blockDim.x + threadIdx.x;
    int stride = gridDim.x * blockDim.x;
    for (int i = idx; i < n4; i += stride) {
        float4 v = x[i];
        float4 o;
        o.x = (v.x >= thr) ? 1.0f : 0.0f;
        o.y = (v.y >= thr) ? 1.0f : 0.0f;
        o.z = (v.z >= thr) ? 1.0f : 0.0f;
        o.w = (v.w >= thr) ? 1.0f : 0.0f;
        out[i] = o;
    }
}

// ---------------- host ----------------
static inline unsigned host_map(float f) {
    unsigned raw; memcpy(&raw, &f, 4);
    return (raw & 0x80000000u) ? ~raw : (raw | 0x80000000u);
}

extern "C" void kernel_launch(void* const* d_in, const int* in_sizes, int n_in,
                              void* d_out, int out_size, void* d_ws, size_t ws_size,
                              hipStream_t stream)
{
    const float* x = (const float*)d_in[0];
    float* out = (float*)d_out;
    long long n = (long long)in_sizes[0];
    long long k = (long long)((double)n * 0.9);   // matches Python int(n * RATIO)

    if (k <= 0) {
        hipMemsetAsync(d_out, 0, (size_t)out_size * sizeof(float), stream);
        return;
    }

    unsigned* ws = (unsigned*)d_ws;
    unsigned* st = ws;
    int n4 = (int)(n / 4);
    const uint4* x4 = (const uint4*)x;
    unsigned r = (unsigned)(n - k);               // ascending rank of threshold

    size_t need_fast = ((size_t)CAND_OFF + (size_t)NBLK * BSEG * 2) * 4;

    if (ws_size >= need_fast) {
        unsigned* hwin = ws + HWIN_OFF;
        unsigned* fb1  = ws + FB1_OFF;
        unsigned* fb2  = ws + FB2_OFF;
        unsigned* fb3  = ws + FB3_OFF;
        unsigned* cntb = ws + CNTB_OFF;
        uint2*    cand = (uint2*)(ws + CAND_OFF);

        // Static window around the 0.1-quantile of N(0,1), u* = map(-1.2816):
        // window = 16384 ulp ~= +-4.7 sigma of the sample-quantile position.
        // Exactness NEVER depends on it: flag-verified, fallback-gated.
        unsigned ustar = host_map(-1.2816f);
        unsigned u0 = ustar - (unsigned)(NWIN / 2);

        zero_ws<<<64, 256, 0, stream>>>((uint4*)d_ws, (FIXED_Z + 3) / 4);
        k1_fused<<<NBLK, 256, 0, stream>>>(x4, n4, (float4*)out, st, hwin,
                                           cand, cntb, u0);
        anchor_select<<<1, 1024, 0, stream>>>(hwin, cntb, r, u0, st);
        fixup<<<NBLK, 64, 0, stream>>>(cand, cntb, st, out);
        // fallback chain (gated on flag!=0) — proven exact path, writes st[9]
        hist_pass<<<1024, 256, 0, stream>>>(x4, n4, 20, 4096, 0, &st[10], fb1, &st[3]);
        scan_select<<<1, 1024, 0, stream>>>(fb1, 4096, nullptr, r, &st[10], &st[11], &st[3], 1);
        hist_pass<<<1024, 256, 0, stream>>>(x4, n4, 8, 4096, 1, &st[10], fb2, &st[3]);
        scan_select<<<1, 1024, 0, stream>>>(fb2, 4096, &st[11], 0u, &st[12], &st[13], &st[3], 1);
        hist_pass<<<1024, 256, 0, stream>>>(x4, n4, 0, 256, 2, &st[10], fb3, &st[3]);
        scan_select<<<1, 1024, 0, stream>>>(fb3, 256, &st[13], 0u, &st[14], &st[15], &st[3], 1);
        finalize_thr_fb<<<1, 1, 0, stream>>>(st, &st[3]);
        mask_kernel<<<2048, 256, 0, stream>>>((const float4*)x, (float4*)out, n4, st, &st[3]);
    } else {
        // small-ws standalone fallback: 3-pass radix + mask (ungated)
        unsigned* h1 = ws + 16;
        unsigned* h2 = ws + 16 + 4096;
        unsigned* h3 = ws + 16 + 8192;

        hipMemsetAsync(d_ws, 0, FB_WS_INTS * sizeof(unsigned), stream);

        hist_pass<<<2048, 256, 0, stream>>>(x4, n4, 20, 4096, 0, &ws[10], h1, nullptr);
        scan_select<<<1, 1024, 0, stream>>>(h1, 4096, nullptr, r, &ws[10], &ws[11], nullptr, 0);
        hist_pass<<<2048, 256, 0, stream>>>(x4, n4, 8, 4096, 1, &ws[10], h2, nullptr);
        scan_select<<<1, 1024, 0, stream>>>(h2, 4096, &ws[11], 0u, &ws[12], &ws[13], nullptr, 0);
        hist_pass<<<2048, 256, 0, stream>>>(x4, n4, 0, 256, 2, &ws[10], h3, nullptr);
        scan_select<<<1, 1024, 0, stream>>>(h3, 256, &ws[13], 0u, &ws[14], &ws[15], nullptr, 0);
        finalize_thr_fb<<<1, 1, 0, stream>>>(ws, nullptr);
        mask_kernel<<<2048, 256, 0, stream>>>((const float4*)x, (float4*)out, n4, ws, nullptr);
    }
}

// Round 18
// 115.923 us; speedup vs baseline: 1.3558x; 1.2412x over previous
//
#include <hip/hip_runtime.h>
#include <string.h>

// Exact k-th order statistic + mask, fp32, n = 64*1024*1024.
// Fused single-full-pass, COUNT-not-histogram anchor + NT mask store:
//   k1_fused : read x, NT-write PROVISIONAL mask (u >= u0+NWIN);
//              per-uint4 below-count -> ONE private-slot LDS atomic;
//              1-ulp window global hist + per-block compaction behind a
//              wave-skippable (98%) combined branch
//   anchor_select : below = st[2]; exact verify + window select -> thr
//   fixup : scatter 1.0f for the ~23K window elems >= thr (gated flag==0)
//   fallback : proven 3-pass radix + FULL re-mask, always enqueued, flag-gated
//
// state: [2]=below [3]=flag [8]=thr mapped-u [9]=thr float bits [10..15]=fb
// ws ints: ST(32)|HWIN(16384)|FB1(4096)|FB2(4096)|FB3(256)|CNTB(2048)
//          <- all zeroed | CAND(2048 blocks x 256 x uint2)

#define N_STATE  32
#define HWIN_OFF 32
#define NWIN     16384
#define FB1_OFF  (HWIN_OFF + NWIN)
#define FB2_OFF  (FB1_OFF + 4096)
#define FB3_OFF  (FB2_OFF + 4096)
#define CNTB_OFF (FB3_OFF + 256)
#define NBLK     2048
#define FIXED_Z  (CNTB_OFF + NBLK)            // ~105 KB zeroed per call
#define CAND_OFF FIXED_Z
#define BSEG     256u

#define FB_WS_INTS (16 + 4096 + 4096 + 256)

typedef float vfloat4 __attribute__((ext_vector_type(4)));

__device__ __forceinline__ unsigned map_bits(unsigned raw) {
    return (raw & 0x80000000u) ? ~raw : (raw | 0x80000000u);
}

// ---------------- workspace zeroing ----------------
__global__ void __launch_bounds__(256)
zero_ws(uint4* __restrict__ p, int n16)
{
    int i = blockIdx.x * 256 + threadIdx.x;
    int s = gridDim.x * 256;
    uint4 z = make_uint4(0u, 0u, 0u, 0u);
    for (; i < n16; i += s) p[i] = z;
}

// ---------------- k1: fused mask + below-count + window compaction ---------
__global__ void __launch_bounds__(256)
k1_fused(const uint4* __restrict__ x, int n4, vfloat4* __restrict__ out,
         unsigned* __restrict__ st, unsigned* __restrict__ hwin,
         uint2* __restrict__ cand, unsigned* __restrict__ cntb, unsigned u0)
{
    __shared__ unsigned c[256];
    __shared__ unsigned bcnt;
    c[threadIdx.x] = 0u;
    if (threadIdx.x == 0) bcnt = 0u;
    __syncthreads();

    uint2* seg = cand + (size_t)blockIdx.x * BSEG;
    const unsigned hiw = u0 + (unsigned)NWIN;
    int idx = blockIdx.x * 256 + threadIdx.x;
    int S = gridDim.x * 256;
    for (int i = idx; i < n4; i += S) {
        uint4 v = x[i];
        vfloat4 o;
        unsigned ua = map_bits(v.x), ub = map_bits(v.y);
        unsigned uc = map_bits(v.z), ud = map_bits(v.w);
        bool ba = ua < u0, bb = ub < u0, bc = uc < u0, bd = ud < u0;
        bool ga = ua >= hiw, gb = ub >= hiw, gc = uc >= hiw, gd = ud >= hiw;
        o[0] = ga ? 1.0f : 0.0f;
        o[1] = gb ? 1.0f : 0.0f;
        o[2] = gc ? 1.0f : 0.0f;
        o[3] = gd ? 1.0f : 0.0f;
        unsigned cnt4 = (ba ? 1u : 0u) + (bb ? 1u : 0u)
                      + (bc ? 1u : 0u) + (bd ? 1u : 0u);
        atomicAdd(&c[threadIdx.x], cnt4);      // private slot: no contention
        bool wa = !(ba | ga), wb = !(bb | gb);
        bool wc = !(bc | gc), wd = !(bd | gd);
        if (wa | wb | wc | wd) {               // wave-skipped ~98% of the time
            unsigned gi = (unsigned)i * 4u;
            if (wa) { atomicAdd(&hwin[ua - u0], 1u);
                      unsigned sl = atomicAdd(&bcnt, 1u);
                      if (sl < BSEG) seg[sl] = make_uint2(ua, gi + 0u); }
            if (wb) { atomicAdd(&hwin[ub - u0], 1u);
                      unsigned sl = atomicAdd(&bcnt, 1u);
                      if (sl < BSEG) seg[sl] = make_uint2(ub, gi + 1u); }
            if (wc) { atomicAdd(&hwin[uc - u0], 1u);
                      unsigned sl = atomicAdd(&bcnt, 1u);
                      if (sl < BSEG) seg[sl] = make_uint2(uc, gi + 2u); }
            if (wd) { atomicAdd(&hwin[ud - u0], 1u);
                      unsigned sl = atomicAdd(&bcnt, 1u);
                      if (sl < BSEG) seg[sl] = make_uint2(ud, gi + 3u); }
        }
        __builtin_nontemporal_store(o, &out[i]);
    }
    __syncthreads();
    for (int off = 128; off > 0; off >>= 1) {
        if (threadIdx.x < (unsigned)off) c[threadIdx.x] += c[threadIdx.x + off];
        __syncthreads();
    }
    if (threadIdx.x == 0) {
        atomicAdd(&st[2], c[0]);
        cntb[blockIdx.x] = bcnt;
    }
}

// ---------------- exact anchor + verification + window select ----------------
__global__ void __launch_bounds__(1024)
anchor_select(const unsigned* __restrict__ hwin, const unsigned* __restrict__ cntb,
              unsigned r, unsigned u0, unsigned* __restrict__ st)
{
    __shared__ unsigned s[1024];
    __shared__ unsigned sm[1024];
    __shared__ unsigned sh_rank, sh_flag, sh_max;
    int t = threadIdx.x;

    // phase 1: max of per-block counts
    unsigned mx = 0;
    for (int j = t; j < NBLK; j += 1024) {
        unsigned cc = cntb[j];
        mx = (cc > mx) ? cc : mx;
    }
    sm[t] = mx;
    __syncthreads();
    for (int off = 512; off > 0; off >>= 1) {
        if (t < off) sm[t] = (sm[t + off] > sm[t]) ? sm[t + off] : sm[t];
        __syncthreads();
    }
    if (t == 0) sh_max = sm[0];
    __syncthreads();

    // phase 2: prefix over hwin (16 bins/thread)
    unsigned loc[16];
    unsigned mySum = 0;
    int base = t * 16;
    #pragma unroll
    for (int j = 0; j < 16; ++j) { loc[j] = hwin[base + j]; mySum += loc[j]; }
    s[t] = mySum;
    __syncthreads();
    for (int off = 1; off < 1024; off <<= 1) {
        unsigned v = (t >= off) ? s[t - off] : 0u;
        __syncthreads();
        s[t] += v;
        __syncthreads();
    }
    unsigned Nwin = s[1023];
    if (t == 0) {
        unsigned long long below = st[2];
        unsigned flag = 0;
        if (sh_max > BSEG) flag = 1;          // block segment overflow
        if (!((below <= (unsigned long long)r) &&
              ((unsigned long long)r < below + (unsigned long long)Nwin))) flag = 1;
        st[3] = flag;
        sh_flag = flag;
        sh_rank = (unsigned)((unsigned long long)r - below);
    }
    __syncthreads();
    if (sh_flag != 0u) return;
    unsigned rank = sh_rank;
    unsigned incl = s[t], excl = incl - mySum;
    if (rank >= excl && rank < incl) {
        unsigned run = excl;
        #pragma unroll
        for (int j = 0; j < 16; ++j) {
            if (rank < run + loc[j]) {
                unsigned u = u0 + (unsigned)(base + j);
                st[8] = u;                                            // mapped thr
                st[9] = (u & 0x80000000u) ? (u & 0x7FFFFFFFu) : ~u;   // float bits
                break;
            }
            run += loc[j];
        }
    }
}

// ---------------- fixup (gated flag==0) ----------------
__global__ void __launch_bounds__(64)
fixup(const uint2* __restrict__ cand, const unsigned* __restrict__ cntb,
      const unsigned* __restrict__ st, float* __restrict__ out)
{
    if (st[3] != 0u) return;
    unsigned thr = st[8];
    unsigned b = blockIdx.x;
    unsigned m = cntb[b]; if (m > BSEG) m = BSEG;
    const uint2* seg = cand + (size_t)b * BSEG;
    for (unsigned j = threadIdx.x; j < m; j += 64u) {
        uint2 cv = seg[j];
        if (cv.x >= thr) out[cv.y] = 1.0f;
    }
}

// ---------------- fallback (proven 3-pass radix), flag-gated ----------------
__global__ void __launch_bounds__(256)
hist_pass(const uint4* __restrict__ x, int n4, int shift, int nbins, int mode,
          const unsigned* __restrict__ state, unsigned* __restrict__ hist,
          const unsigned* __restrict__ gate)
{
    if (gate && *gate == 0u) return;
    __shared__ unsigned lh[4096];
    for (int i = threadIdx.x; i < nbins; i += blockDim.x) lh[i] = 0u;
    __syncthreads();

    unsigned tgt = 0; int mshift = 0;
    if (mode == 1)      { tgt = state[0];                      mshift = 20; }
    else if (mode == 2) { tgt = (state[0] << 12) | state[2];   mshift = 8;  }

    const unsigned binmask = (unsigned)(nbins - 1);
    int idx = blockIdx.x * blockDim.x + threadIdx.x;
    int stride = gridDim.x * blockDim.x;
    for (int i = idx; i < n4; i += stride) {
        uint4 v = x[i];
        unsigned u;
        u = map_bits(v.x); if (!mode || (u >> mshift) == tgt) atomicAdd(&lh[(u >> shift) & binmask], 1u);
        u = map_bits(v.y); if (!mode || (u >> mshift) == tgt) atomicAdd(&lh[(u >> shift) & binmask], 1u);
        u = map_bits(v.z); if (!mode || (u >> mshift) == tgt) atomicAdd(&lh[(u >> shift) & binmask], 1u);
        u = map_bits(v.w); if (!mode || (u >> mshift) == tgt) atomicAdd(&lh[(u >> shift) & binmask], 1u);
    }
    __syncthreads();
    for (int i = threadIdx.x; i < nbins; i += blockDim.x) {
        unsigned c = lh[i];
        if (c) atomicAdd(&hist[i], c);
    }
}

__global__ void __launch_bounds__(1024)
scan_select(const unsigned* __restrict__ hist, int nbins,
            const unsigned* __restrict__ rank_in, unsigned rank_imm,
            unsigned* __restrict__ bin_out, unsigned* __restrict__ rank_out,
            const unsigned* __restrict__ gate, int want_nonzero)
{
    if (gate) {
        unsigned g = *gate;
        if ((g != 0u) != (want_nonzero != 0)) return;
    }
    __shared__ unsigned s[1024];
    int t = threadIdx.x;
    unsigned rank = rank_in ? *rank_in : rank_imm;
    int per = (nbins + 1023) >> 10;
    int base = t * per;
    unsigned mySum = 0;
    for (int i = 0; i < per; ++i) {
        int b = base + i;
        if (b < nbins) mySum += hist[b];
    }
    s[t] = mySum;
    __syncthreads();
    for (int off = 1; off < 1024; off <<= 1) {
        unsigned v = (t >= off) ? s[t - off] : 0u;
        __syncthreads();
        s[t] += v;
        __syncthreads();
    }
    unsigned incl = s[t];
    unsigned excl = incl - mySum;
    if (rank >= excl && rank < incl) {
        unsigned run = excl;
        for (int i = 0; i < per; ++i) {
            int b = base + i;
            unsigned c = (b < nbins) ? hist[b] : 0u;
            if (rank < run + c) { *bin_out = (unsigned)b; *rank_out = rank - run; break; }
            run += c;
        }
    }
}

__global__ void finalize_thr_fb(unsigned* st, const unsigned* gate) {
    if (gate && *gate == 0u) return;
    unsigned u = (st[10] << 20) | (st[12] << 8) | st[14];
    st[9] = (u & 0x80000000u) ? (u & 0x7FFFFFFFu) : ~u;
}

// ---------------- full re-mask (fallback path only, flag-gated) ------------
__global__ void __launch_bounds__(256)
mask_kernel(const float4* __restrict__ x, float4* __restrict__ out, int n4,
            const unsigned* __restrict__ st, const unsigned* __restrict__ gate)
{
    if (gate && *gate == 0u) return;
    float thr = __uint_as_float(st[9]);
    int idx = blockIdx.x * blockDim.x + threadIdx.x;
    int stride = gridDim.x * blockDim.x;
    for (int i = idx; i < n4; i += stride) {
        float4 v = x[i];
        float4 o;
        o.x = (v.x >= thr) ? 1.0f : 0.0f;
        o.y = (v.y >= thr) ? 1.0f : 0.0f;
        o.z = (v.z >= thr) ? 1.0f : 0.0f;
        o.w = (v.w >= thr) ? 1.0f : 0.0f;
        out[i] = o;
    }
}

// ---------------- host ----------------
static inline unsigned host_map(float f) {
    unsigned raw; memcpy(&raw, &f, 4);
    return (raw & 0x80000000u) ? ~raw : (raw | 0x80000000u);
}

extern "C" void kernel_launch(void* const* d_in, const int* in_sizes, int n_in,
                              void* d_out, int out_size, void* d_ws, size_t ws_size,
                              hipStream_t stream)
{
    const float* x = (const float*)d_in[0];
    float* out = (float*)d_out;
    long long n = (long long)in_sizes[0];
    long long k = (long long)((double)n * 0.9);   // matches Python int(n * RATIO)

    if (k <= 0) {
        hipMemsetAsync(d_out, 0, (size_t)out_size * sizeof(float), stream);
        return;
    }

    unsigned* ws = (unsigned*)d_ws;
    unsigned* st = ws;
    int n4 = (int)(n / 4);
    const uint4* x4 = (const uint4*)x;
    unsigned r = (unsigned)(n - k);               // ascending rank of threshold

    size_t need_fast = ((size_t)CAND_OFF + (size_t)NBLK * BSEG * 2) * 4;

    if (ws_size >= need_fast) {
        unsigned* hwin = ws + HWIN_OFF;
        unsigned* fb1  = ws + FB1_OFF;
        unsigned* fb2  = ws + FB2_OFF;
        unsigned* fb3  = ws + FB3_OFF;
        unsigned* cntb = ws + CNTB_OFF;
        uint2*    cand = (uint2*)(ws + CAND_OFF);

        // Static window around the 0.1-quantile of N(0,1), u* = map(-1.2816):
        // window = 16384 ulp ~= +-4.7 sigma of the sample-quantile position.
        // Exactness NEVER depends on it: flag-verified, fallback-gated.
        unsigned ustar = host_map(-1.2816f);
        unsigned u0 = ustar - (unsigned)(NWIN / 2);

        zero_ws<<<64, 256, 0, stream>>>((uint4*)d_ws, (FIXED_Z + 3) / 4);
        k1_fused<<<NBLK, 256, 0, stream>>>(x4, n4, (vfloat4*)out, st, hwin,
                                           cand, cntb, u0);
        anchor_select<<<1, 1024, 0, stream>>>(hwin, cntb, r, u0, st);
        fixup<<<NBLK, 64, 0, stream>>>(cand, cntb, st, out);
        // fallback chain (gated on flag!=0) — proven exact path, writes st[9]
        hist_pass<<<1024, 256, 0, stream>>>(x4, n4, 20, 4096, 0, &st[10], fb1, &st[3]);
        scan_select<<<1, 1024, 0, stream>>>(fb1, 4096, nullptr, r, &st[10], &st[11], &st[3], 1);
        hist_pass<<<1024, 256, 0, stream>>>(x4, n4, 8, 4096, 1, &st[10], fb2, &st[3]);
        scan_select<<<1, 1024, 0, stream>>>(fb2, 4096, &st[11], 0u, &st[12], &st[13], &st[3], 1);
        hist_pass<<<1024, 256, 0, stream>>>(x4, n4, 0, 256, 2, &st[10], fb3, &st[3]);
        scan_select<<<1, 1024, 0, stream>>>(fb3, 256, &st[13], 0u, &st[14], &st[15], &st[3], 1);
        finalize_thr_fb<<<1, 1, 0, stream>>>(st, &st[3]);
        mask_kernel<<<2048, 256, 0, stream>>>((const float4*)x, (float4*)out, n4, st, &st[3]);
    } else {
        // small-ws standalone fallback: 3-pass radix + mask (ungated)
        unsigned* h1 = ws + 16;
        unsigned* h2 = ws + 16 + 4096;
        unsigned* h3 = ws + 16 + 8192;

        hipMemsetAsync(d_ws, 0, FB_WS_INTS * sizeof(unsigned), stream);

        hist_pass<<<2048, 256, 0, stream>>>(x4, n4, 20, 4096, 0, &ws[10], h1, nullptr);
        scan_select<<<1, 1024, 0, stream>>>(h1, 4096, nullptr, r, &ws[10], &ws[11], nullptr, 0);
        hist_pass<<<2048, 256, 0, stream>>>(x4, n4, 8, 4096, 1, &ws[10], h2, nullptr);
        scan_select<<<1, 1024, 0, stream>>>(h2, 4096, &ws[11], 0u, &ws[12], &ws[13], nullptr, 0);
        hist_pass<<<2048, 256, 0, stream>>>(x4, n4, 0, 256, 2, &ws[10], h3, nullptr);
        scan_select<<<1, 1024, 0, stream>>>(h3, 256, &ws[13], 0u, &ws[14], &ws[15], nullptr, 0);
        finalize_thr_fb<<<1, 1, 0, stream>>>(ws, nullptr);
        mask_kernel<<<2048, 256, 0, stream>>>((const float4*)x, (float4*)out, n4, ws, nullptr);
    }
}

// Round 19
// 106.620 us; speedup vs baseline: 1.4741x; 1.0873x over previous
//
#include <hip/hip_runtime.h>
#include <string.h>

// Exact k-th order statistic + mask, fp32, n = 64*1024*1024.
// Fused single-full-pass + minimal dispatch count (6 kernels on fast path):
//   k1_fused : read x, NT-write PROVISIONAL mask (u >= u0+NWIN);
//              per-uint4 below-count -> ONE private-slot LDS atomic;
//              1-ulp window global hist + per-block compaction behind a
//              wave-skippable (98%) combined branch
//   anchor_select : below = st[2]; exact verify + window select -> thr
//   fixup : scatter 1.0f for the ~23K window elems >= thr (gated flag==0)
//   fb_all : ONE gated kernel = complete 3-pass radix select (single block,
//            slow but never taken) -> st[9]; gated full re-mask after it.
//
// state: [2]=below [3]=flag [8]=thr mapped-u [9]=thr float bits
// ws ints: ST(32)|HWIN(16384)|CNTB(2048) <- zeroed | CAND(2048 x 256 x uint2)

#define N_STATE  32
#define HWIN_OFF 32
#define NWIN     16384
#define CNTB_OFF (HWIN_OFF + NWIN)
#define NBLK     2048
#define FIXED_Z  (CNTB_OFF + NBLK)            // ~74 KB zeroed per call
#define CAND_OFF FIXED_Z
#define BSEG     256u

#define FB_WS_INTS (16 + 4096 + 4096 + 256)

typedef float vfloat4 __attribute__((ext_vector_type(4)));

__device__ __forceinline__ unsigned map_bits(unsigned raw) {
    return (raw & 0x80000000u) ? ~raw : (raw | 0x80000000u);
}

// ---------------- workspace zeroing ----------------
__global__ void __launch_bounds__(256)
zero_ws(uint4* __restrict__ p, int n16)
{
    int i = blockIdx.x * 256 + threadIdx.x;
    int s = gridDim.x * 256;
    uint4 z = make_uint4(0u, 0u, 0u, 0u);
    for (; i < n16; i += s) p[i] = z;
}

// ---------------- k1: fused mask + below-count + window compaction ---------
__global__ void __launch_bounds__(256)
k1_fused(const uint4* __restrict__ x, int n4, vfloat4* __restrict__ out,
         unsigned* __restrict__ st, unsigned* __restrict__ hwin,
         uint2* __restrict__ cand, unsigned* __restrict__ cntb, unsigned u0)
{
    __shared__ unsigned c[256];
    __shared__ unsigned bcnt;
    c[threadIdx.x] = 0u;
    if (threadIdx.x == 0) bcnt = 0u;
    __syncthreads();

    uint2* seg = cand + (size_t)blockIdx.x * BSEG;
    const unsigned hiw = u0 + (unsigned)NWIN;
    int idx = blockIdx.x * 256 + threadIdx.x;
    int S = gridDim.x * 256;
    for (int i = idx; i < n4; i += S) {
        uint4 v = x[i];
        vfloat4 o;
        unsigned ua = map_bits(v.x), ub = map_bits(v.y);
        unsigned uc = map_bits(v.z), ud = map_bits(v.w);
        bool ba = ua < u0, bb = ub < u0, bc = uc < u0, bd = ud < u0;
        bool ga = ua >= hiw, gb = ub >= hiw, gc = uc >= hiw, gd = ud >= hiw;
        o[0] = ga ? 1.0f : 0.0f;
        o[1] = gb ? 1.0f : 0.0f;
        o[2] = gc ? 1.0f : 0.0f;
        o[3] = gd ? 1.0f : 0.0f;
        unsigned cnt4 = (ba ? 1u : 0u) + (bb ? 1u : 0u)
                      + (bc ? 1u : 0u) + (bd ? 1u : 0u);
        atomicAdd(&c[threadIdx.x], cnt4);      // private slot: no contention
        bool wa = !(ba | ga), wb = !(bb | gb);
        bool wc = !(bc | gc), wd = !(bd | gd);
        if (wa | wb | wc | wd) {               // wave-skipped ~98% of the time
            unsigned gi = (unsigned)i * 4u;
            if (wa) { atomicAdd(&hwin[ua - u0], 1u);
                      unsigned sl = atomicAdd(&bcnt, 1u);
                      if (sl < BSEG) seg[sl] = make_uint2(ua, gi + 0u); }
            if (wb) { atomicAdd(&hwin[ub - u0], 1u);
                      unsigned sl = atomicAdd(&bcnt, 1u);
                      if (sl < BSEG) seg[sl] = make_uint2(ub, gi + 1u); }
            if (wc) { atomicAdd(&hwin[uc - u0], 1u);
                      unsigned sl = atomicAdd(&bcnt, 1u);
                      if (sl < BSEG) seg[sl] = make_uint2(uc, gi + 2u); }
            if (wd) { atomicAdd(&hwin[ud - u0], 1u);
                      unsigned sl = atomicAdd(&bcnt, 1u);
                      if (sl < BSEG) seg[sl] = make_uint2(ud, gi + 3u); }
        }
        __builtin_nontemporal_store(o, &out[i]);
    }
    __syncthreads();
    for (int off = 128; off > 0; off >>= 1) {
        if (threadIdx.x < (unsigned)off) c[threadIdx.x] += c[threadIdx.x + off];
        __syncthreads();
    }
    if (threadIdx.x == 0) {
        atomicAdd(&st[2], c[0]);
        cntb[blockIdx.x] = bcnt;
    }
}

// ---------------- exact anchor + verification + window select ----------------
__global__ void __launch_bounds__(1024)
anchor_select(const unsigned* __restrict__ hwin, const unsigned* __restrict__ cntb,
              unsigned r, unsigned u0, unsigned* __restrict__ st)
{
    __shared__ unsigned s[1024];
    __shared__ unsigned sm[1024];
    __shared__ unsigned sh_rank, sh_flag, sh_max;
    int t = threadIdx.x;

    // phase 1: max of per-block counts
    unsigned mx = 0;
    for (int j = t; j < NBLK; j += 1024) {
        unsigned cc = cntb[j];
        mx = (cc > mx) ? cc : mx;
    }
    sm[t] = mx;
    __syncthreads();
    for (int off = 512; off > 0; off >>= 1) {
        if (t < off) sm[t] = (sm[t + off] > sm[t]) ? sm[t + off] : sm[t];
        __syncthreads();
    }
    if (t == 0) sh_max = sm[0];
    __syncthreads();

    // phase 2: prefix over hwin (16 bins/thread)
    unsigned loc[16];
    unsigned mySum = 0;
    int base = t * 16;
    #pragma unroll
    for (int j = 0; j < 16; ++j) { loc[j] = hwin[base + j]; mySum += loc[j]; }
    s[t] = mySum;
    __syncthreads();
    for (int off = 1; off < 1024; off <<= 1) {
        unsigned v = (t >= off) ? s[t - off] : 0u;
        __syncthreads();
        s[t] += v;
        __syncthreads();
    }
    unsigned Nwin = s[1023];
    if (t == 0) {
        unsigned long long below = st[2];
        unsigned flag = 0;
        if (sh_max > BSEG) flag = 1;          // block segment overflow
        if (!((below <= (unsigned long long)r) &&
              ((unsigned long long)r < below + (unsigned long long)Nwin))) flag = 1;
        st[3] = flag;
        sh_flag = flag;
        sh_rank = (unsigned)((unsigned long long)r - below);
    }
    __syncthreads();
    if (sh_flag != 0u) return;
    unsigned rank = sh_rank;
    unsigned incl = s[t], excl = incl - mySum;
    if (rank >= excl && rank < incl) {
        unsigned run = excl;
        #pragma unroll
        for (int j = 0; j < 16; ++j) {
            if (rank < run + loc[j]) {
                unsigned u = u0 + (unsigned)(base + j);
                st[8] = u;                                            // mapped thr
                st[9] = (u & 0x80000000u) ? (u & 0x7FFFFFFFu) : ~u;   // float bits
                break;
            }
            run += loc[j];
        }
    }
}

// ---------------- fixup (gated flag==0) ----------------
__global__ void __launch_bounds__(64)
fixup(const uint2* __restrict__ cand, const unsigned* __restrict__ cntb,
      const unsigned* __restrict__ st, float* __restrict__ out)
{
    if (st[3] != 0u) return;
    unsigned thr = st[8];
    unsigned b = blockIdx.x;
    unsigned m = cntb[b]; if (m > BSEG) m = BSEG;
    const uint2* seg = cand + (size_t)b * BSEG;
    for (unsigned j = threadIdx.x; j < m; j += 64u) {
        uint2 cv = seg[j];
        if (cv.x >= thr) out[cv.y] = 1.0f;
    }
}

// ---------------- in-block select helper (1024 threads) ----------------
__device__ __forceinline__ void block_select1024(
    const unsigned* __restrict__ h, int nbins, unsigned rank,
    unsigned* s, unsigned* sh_bin, unsigned* sh_rank)
{
    int t = threadIdx.x;
    int per = (nbins + 1023) >> 10;
    int base = t * per;
    unsigned mySum = 0;
    for (int j = 0; j < per; ++j) {
        int b = base + j;
        if (b < nbins) mySum += h[b];
    }
    s[t] = mySum;
    __syncthreads();
    for (int off = 1; off < 1024; off <<= 1) {
        unsigned v = (t >= off) ? s[t - off] : 0u;
        __syncthreads();
        s[t] += v;
        __syncthreads();
    }
    unsigned incl = s[t], excl = incl - mySum;
    if (rank >= excl && rank < incl) {
        unsigned run = excl;
        for (int j = 0; j < per; ++j) {
            int b = base + j;
            unsigned c = (b < nbins) ? h[b] : 0u;
            if (rank < run + c) { *sh_bin = (unsigned)b; *sh_rank = rank - run; break; }
            run += c;
        }
    }
    __syncthreads();
}

// ---------------- fb_all: complete 3-pass radix select, ONE gated kernel ----
// Single block; only runs if flag!=0 (correctness insurance, never taken for
// in-distribution data). Slow-if-taken is acceptable.
__global__ void __launch_bounds__(1024)
fb_all(const uint4* __restrict__ x, int n4, unsigned r, unsigned* __restrict__ st)
{
    if (st[3] == 0u) return;
    __shared__ unsigned h[4096];
    __shared__ unsigned s[1024];
    __shared__ unsigned sh_bin, sh_rank;
    int t = threadIdx.x;

    // pass 1: top-12 bits
    for (int i = t; i < 4096; i += 1024) h[i] = 0u;
    __syncthreads();
    for (int i = t; i < n4; i += 1024) {
        uint4 v = x[i];
        atomicAdd(&h[map_bits(v.x) >> 20], 1u);
        atomicAdd(&h[map_bits(v.y) >> 20], 1u);
        atomicAdd(&h[map_bits(v.z) >> 20], 1u);
        atomicAdd(&h[map_bits(v.w) >> 20], 1u);
    }
    __syncthreads();
    block_select1024(h, 4096, r, s, &sh_bin, &sh_rank);
    unsigned b1 = sh_bin, r2 = sh_rank;
    __syncthreads();

    // pass 2: mid-12 bits within b1
    for (int i = t; i < 4096; i += 1024) h[i] = 0u;
    __syncthreads();
    for (int i = t; i < n4; i += 1024) {
        uint4 v = x[i];
        unsigned u;
        u = map_bits(v.x); if ((u >> 20) == b1) atomicAdd(&h[(u >> 8) & 4095u], 1u);
        u = map_bits(v.y); if ((u >> 20) == b1) atomicAdd(&h[(u >> 8) & 4095u], 1u);
        u = map_bits(v.z); if ((u >> 20) == b1) atomicAdd(&h[(u >> 8) & 4095u], 1u);
        u = map_bits(v.w); if ((u >> 20) == b1) atomicAdd(&h[(u >> 8) & 4095u], 1u);
    }
    __syncthreads();
    block_select1024(h, 4096, r2, s, &sh_bin, &sh_rank);
    unsigned b2 = sh_bin, r3 = sh_rank;
    __syncthreads();

    // pass 3: low-8 bits within (b1,b2)
    for (int i = t; i < 4096; i += 1024) h[i] = 0u;
    __syncthreads();
    unsigned pfx = (b1 << 12) | b2;
    for (int i = t; i < n4; i += 1024) {
        uint4 v = x[i];
        unsigned u;
        u = map_bits(v.x); if ((u >> 8) == pfx) atomicAdd(&h[u & 255u], 1u);
        u = map_bits(v.y); if ((u >> 8) == pfx) atomicAdd(&h[u & 255u], 1u);
        u = map_bits(v.z); if ((u >> 8) == pfx) atomicAdd(&h[u & 255u], 1u);
        u = map_bits(v.w); if ((u >> 8) == pfx) atomicAdd(&h[u & 255u], 1u);
    }
    __syncthreads();
    block_select1024(h, 256, r3, s, &sh_bin, &sh_rank);
    if (t == 0) {
        unsigned u = (b1 << 20) | (b2 << 8) | sh_bin;
        st[9] = (u & 0x80000000u) ? (u & 0x7FFFFFFFu) : ~u;   // inverse map
    }
}

// ---------------- full re-mask (fallback path only, flag-gated) ------------
__global__ void __launch_bounds__(256)
mask_kernel(const float4* __restrict__ x, float4* __restrict__ out, int n4,
            const unsigned* __restrict__ st, const unsigned* __restrict__ gate)
{
    if (gate && *gate == 0u) return;
    float thr = __uint_as_float(st[9]);
    int idx = blockIdx.x * blockDim.x + threadIdx.x;
    int stride = gridDim.x * blockDim.x;
    for (int i = idx; i < n4; i += stride) {
        float4 v = x[i];
        float4 o;
        o.x = (v.x >= thr) ? 1.0f : 0.0f;
        o.y = (v.y >= thr) ? 1.0f : 0.0f;
        o.z = (v.z >= thr) ? 1.0f : 0.0f;
        o.w = (v.w >= thr) ? 1.0f : 0.0f;
        out[i] = o;
    }
}

// ---------------- small-ws standalone fallback kernels ----------------
__global__ void __launch_bounds__(256)
hist_pass(const uint4* __restrict__ x, int n4, int shift, int nbins, int mode,
          const unsigned* __restrict__ state, unsigned* __restrict__ hist,
          const unsigned* __restrict__ gate)
{
    if (gate && *gate == 0u) return;
    __shared__ unsigned lh[4096];
    for (int i = threadIdx.x; i < nbins; i += blockDim.x) lh[i] = 0u;
    __syncthreads();

    unsigned tgt = 0; int mshift = 0;
    if (mode == 1)      { tgt = state[0];                      mshift = 20; }
    else if (mode == 2) { tgt = (state[0] << 12) | state[2];   mshift = 8;  }

    const unsigned binmask = (unsigned)(nbins - 1);
    int idx = blockIdx.x * blockDim.x + threadIdx.x;
    int stride = gridDim.x * blockDim.x;
    for (int i = idx; i < n4; i += stride) {
        uint4 v = x[i];
        unsigned u;
        u = map_bits(v.x); if (!mode || (u >> mshift) == tgt) atomicAdd(&lh[(u >> shift) & binmask], 1u);
        u = map_bits(v.y); if (!mode || (u >> mshift) == tgt) atomicAdd(&lh[(u >> shift) & binmask], 1u);
        u = map_bits(v.z); if (!mode || (u >> mshift) == tgt) atomicAdd(&lh[(u >> shift) & binmask], 1u);
        u = map_bits(v.w); if (!mode || (u >> mshift) == tgt) atomicAdd(&lh[(u >> shift) & binmask], 1u);
    }
    __syncthreads();
    for (int i = threadIdx.x; i < nbins; i += blockDim.x) {
        unsigned c = lh[i];
        if (c) atomicAdd(&hist[i], c);
    }
}

__global__ void __launch_bounds__(1024)
scan_select(const unsigned* __restrict__ hist, int nbins,
            const unsigned* __restrict__ rank_in, unsigned rank_imm,
            unsigned* __restrict__ bin_out, unsigned* __restrict__ rank_out,
            const unsigned* __restrict__ gate, int want_nonzero)
{
    if (gate) {
        unsigned g = *gate;
        if ((g != 0u) != (want_nonzero != 0)) return;
    }
    __shared__ unsigned s[1024];
    int t = threadIdx.x;
    unsigned rank = rank_in ? *rank_in : rank_imm;
    int per = (nbins + 1023) >> 10;
    int base = t * per;
    unsigned mySum = 0;
    for (int i = 0; i < per; ++i) {
        int b = base + i;
        if (b < nbins) mySum += hist[b];
    }
    s[t] = mySum;
    __syncthreads();
    for (int off = 1; off < 1024; off <<= 1) {
        unsigned v = (t >= off) ? s[t - off] : 0u;
        __syncthreads();
        s[t] += v;
        __syncthreads();
    }
    unsigned incl = s[t];
    unsigned excl = incl - mySum;
    if (rank >= excl && rank < incl) {
        unsigned run = excl;
        for (int i = 0; i < per; ++i) {
            int b = base + i;
            unsigned c = (b < nbins) ? hist[b] : 0u;
            if (rank < run + c) { *bin_out = (unsigned)b; *rank_out = rank - run; break; }
            run += c;
        }
    }
}

__global__ void finalize_thr_fb(unsigned* st, const unsigned* gate) {
    if (gate && *gate == 0u) return;
    unsigned u = (st[10] << 20) | (st[12] << 8) | st[14];
    st[9] = (u & 0x80000000u) ? (u & 0x7FFFFFFFu) : ~u;
}

// ---------------- host ----------------
static inline unsigned host_map(float f) {
    unsigned raw; memcpy(&raw, &f, 4);
    return (raw & 0x80000000u) ? ~raw : (raw | 0x80000000u);
}

extern "C" void kernel_launch(void* const* d_in, const int* in_sizes, int n_in,
                              void* d_out, int out_size, void* d_ws, size_t ws_size,
                              hipStream_t stream)
{
    const float* x = (const float*)d_in[0];
    float* out = (float*)d_out;
    long long n = (long long)in_sizes[0];
    long long k = (long long)((double)n * 0.9);   // matches Python int(n * RATIO)

    if (k <= 0) {
        hipMemsetAsync(d_out, 0, (size_t)out_size * sizeof(float), stream);
        return;
    }

    unsigned* ws = (unsigned*)d_ws;
    unsigned* st = ws;
    int n4 = (int)(n / 4);
    const uint4* x4 = (const uint4*)x;
    unsigned r = (unsigned)(n - k);               // ascending rank of threshold

    size_t need_fast = ((size_t)CAND_OFF + (size_t)NBLK * BSEG * 2) * 4;

    if (ws_size >= need_fast) {
        unsigned* hwin = ws + HWIN_OFF;
        unsigned* cntb = ws + CNTB_OFF;
        uint2*    cand = (uint2*)(ws + CAND_OFF);

        // Static window around the 0.1-quantile of N(0,1), u* = map(-1.2816):
        // window = 16384 ulp ~= +-4.7 sigma of the sample-quantile position.
        // Exactness NEVER depends on it: flag-verified; fb_all re-solves
        // exactly (any data) and the gated re-mask rewrites the full output.
        unsigned ustar = host_map(-1.2816f);
        unsigned u0 = ustar - (unsigned)(NWIN / 2);

        zero_ws<<<64, 256, 0, stream>>>((uint4*)d_ws, (FIXED_Z + 3) / 4);
        k1_fused<<<NBLK, 256, 0, stream>>>(x4, n4, (vfloat4*)out, st, hwin,
                                           cand, cntb, u0);
        anchor_select<<<1, 1024, 0, stream>>>(hwin, cntb, r, u0, st);
        fixup<<<NBLK, 64, 0, stream>>>(cand, cntb, st, out);
        fb_all<<<1, 1024, 0, stream>>>(x4, n4, r, st);
        mask_kernel<<<2048, 256, 0, stream>>>((const float4*)x, (float4*)out, n4, st, &st[3]);
    } else {
        // small-ws standalone fallback: 3-pass radix + mask (ungated)
        unsigned* h1 = ws + 16;
        unsigned* h2 = ws + 16 + 4096;
        unsigned* h3 = ws + 16 + 8192;

        hipMemsetAsync(d_ws, 0, FB_WS_INTS * sizeof(unsigned), stream);

        hist_pass<<<2048, 256, 0, stream>>>(x4, n4, 20, 4096, 0, &ws[10], h1, nullptr);
        scan_select<<<1, 1024, 0, stream>>>(h1, 4096, nullptr, r, &ws[10], &ws[11], nullptr, 0);
        hist_pass<<<2048, 256, 0, stream>>>(x4, n4, 8, 4096, 1, &ws[10], h2, nullptr);
        scan_select<<<1, 1024, 0, stream>>>(h2, 4096, &ws[11], 0u, &ws[12], &ws[13], nullptr, 0);
        hist_pass<<<2048, 256, 0, stream>>>(x4, n4, 0, 256, 2, &ws[10], h3, nullptr);
        scan_select<<<1, 1024, 0, stream>>>(h3, 256, &ws[13], 0u, &ws[14], &ws[15], nullptr, 0);
        finalize_thr_fb<<<1, 1, 0, stream>>>(ws, nullptr);
        mask_kernel<<<2048, 256, 0, stream>>>((const float4*)x, (float4*)out, n4, ws, nullptr);
    }
}